// Round 1
// baseline (55.878 us; speedup 1.0000x reference)
//
#include <hip/hip_runtime.h>

#define NM  512   // N_MODES
#define KTH 511   // number of thetas = N_MODES - 1

// One wave (64 lanes) per row r of U.
// Row r of U (row-major):
//   U[r][j] = 0                      for j > r+1
//   U[r][r+1] = sin(theta_r)         (r <= 510)
//   cascade: Q = cos(theta_r) (or 1 for r=511);
//            for i = r-1 .. 0: U[r][i+1] = cos(theta_i)*Q; Q *= -sin(theta_i);
//            U[r][0] = Q
// Each lane handles 8 consecutive chain positions m = lane*8 .. lane*8+7
// (m = r-1-i); a wave-wide multiplicative exclusive scan of the per-lane
// products of (-sin) gives each lane its chain starting value.
__global__ __launch_bounds__(64) void unitary_rows(const float* __restrict__ thetas,
                                                   float* __restrict__ U) {
    const int r    = blockIdx.x;    // row 0..511
    const int lane = threadIdx.x;   // 0..63

    __shared__ float row[NM];

    // zero-init the row buffer (upper part of the row stays 0)
    #pragma unroll
    for (int k = 0; k < NM / 64; ++k) row[lane + 64 * k] = 0.0f;
    __syncthreads();

    const int   L  = r;                                     // cascade length
    const float cr = (r < KTH) ? cosf(thetas[r]) : 1.0f;    // chain seed

    // per-lane chunk: local sin/cos and product of (-s_i)
    float sv[8], cv[8];
    float p = 1.0f;
    #pragma unroll
    for (int mm = 0; mm < 8; ++mm) {
        const int m = lane * 8 + mm;
        if (m < L) {
            const int   i  = r - 1 - m;
            const float th = thetas[i];
            sv[mm] = sinf(th);
            cv[mm] = cosf(th);
            p *= -sv[mm];
        } else {
            sv[mm] = 0.0f;
            cv[mm] = 0.0f;
        }
    }

    // inclusive multiplicative scan across 64 lanes
    float x = p;
    #pragma unroll
    for (int off = 1; off < 64; off <<= 1) {
        const float y = __shfl_up(x, off, 64);
        if (lane >= off) x *= y;
    }
    // exclusive prefix product for this lane
    float pre = __shfl_up(x, 1, 64);
    if (lane == 0) pre = 1.0f;

    // walk this lane's 8 chain positions
    float Q = cr * pre;
    #pragma unroll
    for (int mm = 0; mm < 8; ++mm) {
        const int m = lane * 8 + mm;
        if (m < L) {
            const int i = r - 1 - m;
            row[i + 1] = cv[mm] * Q;
            Q          = -sv[mm] * Q;
            if (m == L - 1) row[0] = Q;   // end of chain writes column 0
        }
    }
    if (r == 0 && lane == 0) row[0] = cr;                     // empty chain case
    if (r < KTH && lane == 0) row[r + 1] = sinf(thetas[r]);   // super-diagonal
    __syncthreads();

    // coalesced dump: 2 x float4 per lane = 512 floats
    float4*       dst = (float4*)(U + (size_t)r * NM);
    const float4* src = (const float4*)row;
    dst[lane]      = src[lane];
    dst[lane + 64] = src[lane + 64];
}

extern "C" void kernel_launch(void* const* d_in, const int* in_sizes, int n_in,
                              void* d_out, int out_size, void* d_ws, size_t ws_size,
                              hipStream_t stream) {
    const float* thetas = (const float*)d_in[0];
    float*       U      = (float*)d_out;
    unitary_rows<<<NM, 64, 0, stream>>>(thetas, U);
}